// Round 5
// baseline (164.829 us; speedup 1.0000x reference)
//
#include <hip/hip_runtime.h>

// PointPillarScatter: scatter sparse pillar features into a dense BEV grid.
// Grid: NX=432, NY=496, NZ=1, C=64, B=8, P=96000 pillars (5.6% occupancy).
// Out 0: [B, C, NY, NX] f32 ; Out 1: [B, 1, NY, NX] f32, concatenated flat.
//
// Round-4: same as round-3 plan (linear-sweep gather + nontemporal stores +
// 2 independent float4s/thread), with the store type fixed: clang's
// __builtin_nontemporal_store needs a native vector type, not HIP's float4
// class. Use ext_vector_type(4) float.

namespace {

constexpr int kNX = 432;
constexpr int kNY = 496;
constexpr int kS  = kNX * kNY;   // 214272 spatial cells per sample
constexpr int kS4 = kS / 4;      // 53568 float4s per plane
constexpr int kC  = 64;
constexpr int kB  = 8;

typedef float f32x4 __attribute__((ext_vector_type(4)));

__global__ void scatter_idx_kernel(const int* __restrict__ coords,
                                   int* __restrict__ map,
                                   int P, int BS) {
  int p = blockIdx.x * blockDim.x + threadIdx.x;
  if (p >= P) return;
  // coords row p = (b, z, y, x) as int32
  int4 c = reinterpret_cast<const int4*>(coords)[p];
  long flat = (long)c.x * kS + (long)c.y + (long)c.z * kNX + (long)c.w;
  if (flat >= 0 && flat < (long)BS) map[(int)flat] = p;
}

// Thread t owns output float4s g = t and g = t + half (half = total4/2).
// plane 0..511   -> out0 (b = plane>>6, c = plane&63)
// plane 512..519 -> out1 (b = plane-512)
__global__ __launch_bounds__(256) void gather_fill_kernel(
    const int* __restrict__ map,     // [B*S] pillar index or -1
    const float* __restrict__ pf,    // [P, 64]
    const float* __restrict__ vnp,   // [P]
    float* __restrict__ out,
    int half) {
  int t = blockIdx.x * blockDim.x + threadIdx.x;
  if (t >= half) return;
  const int4* __restrict__ map4 = reinterpret_cast<const int4*>(map);

  #pragma unroll
  for (int k = 0; k < 2; ++k) {
    int g = t + k * half;
    int plane = g / kS4;               // const-div -> mul_hi
    int j = g - plane * kS4;

    f32x4 v = (f32x4)(0.f);
    if (plane < kB * kC) {
      int b = plane >> 6;
      int c = plane & 63;
      int4 m = map4[b * kS4 + j];
      if (m.x >= 0) v.x = pf[m.x * kC + c];
      if (m.y >= 0) v.y = pf[m.y * kC + c];
      if (m.z >= 0) v.z = pf[m.z * kC + c];
      if (m.w >= 0) v.w = pf[m.w * kC + c];
    } else {
      int b = plane - kB * kC;
      int4 m = map4[b * kS4 + j];
      if (m.x >= 0) v.x = vnp[m.x];
      if (m.y >= 0) v.y = vnp[m.y];
      if (m.z >= 0) v.z = vnp[m.z];
      if (m.w >= 0) v.w = vnp[m.w];
    }
    // streaming store: evict-first in L2, keep the map resident
    __builtin_nontemporal_store(v, reinterpret_cast<f32x4*>(out) + g);
  }
}

// ---- fallback if ws_size is too small for the map: memset + direct scatter
__global__ void direct_scatter_kernel(const int* __restrict__ coords,
                                      const float* __restrict__ pf,
                                      const float* __restrict__ vnp,
                                      float* __restrict__ out,
                                      int P, int B) {
  int p = blockIdx.x;          // one wave per pillar
  int c = threadIdx.x;         // 64 channels
  if (p >= P) return;
  int4 cc = reinterpret_cast<const int4*>(coords)[p];
  int b = cc.x;
  int s = cc.y + cc.z * kNX + cc.w;
  out[(b * kC + c) * kS + s] = pf[p * kC + c];
  if (c == 0) out[B * kC * kS + b * kS + s] = vnp[p];
}

}  // namespace

extern "C" void kernel_launch(void* const* d_in, const int* in_sizes, int n_in,
                              void* d_out, int out_size, void* d_ws, size_t ws_size,
                              hipStream_t stream) {
  const float* pf     = (const float*)d_in[0];  // [P,64] f32
  const int*   coords = (const int*)d_in[1];    // [P,4] int32 (b,z,y,x)
  const float* vnp    = (const float*)d_in[2];  // [P] f32
  const int B = kB;                              // fixed by problem config
  const int P = in_sizes[0] / kC;
  const int BS = B * kS;                         // 1,714,176
  float* out = (float*)d_out;

  const size_t map_bytes = (size_t)BS * sizeof(int);
  if (ws_size >= map_bytes) {
    int* map = (int*)d_ws;
    (void)hipMemsetAsync(map, 0xFF, map_bytes, stream);  // all -1
    scatter_idx_kernel<<<(P + 255) / 256, 256, 0, stream>>>(coords, map, P, BS);
    const int total4 = (B * kC * kS + B * kS) / 4;  // 27,855,360 float4s
    const int half = total4 / 2;                    // 13,927,680
    gather_fill_kernel<<<(half + 255) / 256, 256, 0, stream>>>(
        map, pf, vnp, out, half);
  } else {
    (void)hipMemsetAsync(out, 0, (size_t)out_size * sizeof(float), stream);
    direct_scatter_kernel<<<P, 64, 0, stream>>>(coords, pf, vnp, out, P, B);
  }
}

// Round 6
// 164.819 us; speedup vs baseline: 1.0001x; 1.0001x over previous
//
#include <hip/hip_runtime.h>

// PointPillarScatter: scatter sparse pillar features into a dense BEV grid.
// Grid: NX=432, NY=496, NZ=1, C=64, B=8, P=96000 pillars (5.6% occupancy).
// Out 0: [B, C, NY, NX] f32 ; Out 1: [B, 1, NY, NX] f32, concatenated flat.
//
// Round-6: linear-sweep gather (round-3 structure, normal stores), with each
// thread owning TWO CONSECUTIVE float4s (2t, 2t+1). Round-5's regression
// (116.5 -> 164.8 us) is attributed to the g/g+half split doubling the
// concurrent cache working set (two batches' map+pf windows) — so the extra
// per-thread work must stay contiguous. kS4 is even, so both float4s are
// always in the same plane: one div per thread, 2 KB contiguous per wave,
// 2x independent gather chains.

namespace {

constexpr int kNX = 432;
constexpr int kNY = 496;
constexpr int kS  = kNX * kNY;   // 214272 spatial cells per sample
constexpr int kS4 = kS / 4;      // 53568 float4s per plane (even)
constexpr int kC  = 64;
constexpr int kB  = 8;

typedef float f32x4 __attribute__((ext_vector_type(4)));

__global__ void scatter_idx_kernel(const int* __restrict__ coords,
                                   int* __restrict__ map,
                                   int P, int BS) {
  int p = blockIdx.x * blockDim.x + threadIdx.x;
  if (p >= P) return;
  // coords row p = (b, z, y, x) as int32
  int4 c = reinterpret_cast<const int4*>(coords)[p];
  long flat = (long)c.x * kS + (long)c.y + (long)c.z * kNX + (long)c.w;
  if (flat >= 0 && flat < (long)BS) map[(int)flat] = p;
}

// Thread t owns output float4s g = 2t and g = 2t+1 (same plane, same batch).
// plane 0..511   -> out0 (b = plane>>6, c = plane&63)
// plane 512..519 -> out1 (b = plane-512)
__global__ __launch_bounds__(256) void gather_fill_kernel(
    const int* __restrict__ map,     // [B*S] pillar index or -1
    const float* __restrict__ pf,    // [P, 64]
    const float* __restrict__ vnp,   // [P]
    float* __restrict__ out,
    int nthreads) {
  int t = blockIdx.x * blockDim.x + threadIdx.x;
  if (t >= nthreads) return;
  const int4* __restrict__ map4 = reinterpret_cast<const int4*>(map);

  int g0 = t * 2;
  int plane = g0 / kS4;              // const-div -> mul_hi
  int j = g0 - plane * kS4;          // j and j+1 both < kS4 (kS4 even)

  f32x4 v0 = (f32x4)(0.f);
  f32x4 v1 = (f32x4)(0.f);
  if (plane < kB * kC) {
    int b = plane >> 6;
    int c = plane & 63;
    int4 m0 = map4[b * kS4 + j];
    int4 m1 = map4[b * kS4 + j + 1];
    if (m0.x >= 0) v0.x = pf[m0.x * kC + c];
    if (m0.y >= 0) v0.y = pf[m0.y * kC + c];
    if (m0.z >= 0) v0.z = pf[m0.z * kC + c];
    if (m0.w >= 0) v0.w = pf[m0.w * kC + c];
    if (m1.x >= 0) v1.x = pf[m1.x * kC + c];
    if (m1.y >= 0) v1.y = pf[m1.y * kC + c];
    if (m1.z >= 0) v1.z = pf[m1.z * kC + c];
    if (m1.w >= 0) v1.w = pf[m1.w * kC + c];
  } else {
    int b = plane - kB * kC;
    int4 m0 = map4[b * kS4 + j];
    int4 m1 = map4[b * kS4 + j + 1];
    if (m0.x >= 0) v0.x = vnp[m0.x];
    if (m0.y >= 0) v0.y = vnp[m0.y];
    if (m0.z >= 0) v0.z = vnp[m0.z];
    if (m0.w >= 0) v0.w = vnp[m0.w];
    if (m1.x >= 0) v1.x = vnp[m1.x];
    if (m1.y >= 0) v1.y = vnp[m1.y];
    if (m1.z >= 0) v1.z = vnp[m1.z];
    if (m1.w >= 0) v1.w = vnp[m1.w];
  }
  f32x4* __restrict__ out4 = reinterpret_cast<f32x4*>(out);
  out4[g0]     = v0;
  out4[g0 + 1] = v1;
}

// ---- fallback if ws_size is too small for the map: memset + direct scatter
__global__ void direct_scatter_kernel(const int* __restrict__ coords,
                                      const float* __restrict__ pf,
                                      const float* __restrict__ vnp,
                                      float* __restrict__ out,
                                      int P, int B) {
  int p = blockIdx.x;          // one wave per pillar
  int c = threadIdx.x;         // 64 channels
  if (p >= P) return;
  int4 cc = reinterpret_cast<const int4*>(coords)[p];
  int b = cc.x;
  int s = cc.y + cc.z * kNX + cc.w;
  out[(b * kC + c) * kS + s] = pf[p * kC + c];
  if (c == 0) out[B * kC * kS + b * kS + s] = vnp[p];
}

}  // namespace

extern "C" void kernel_launch(void* const* d_in, const int* in_sizes, int n_in,
                              void* d_out, int out_size, void* d_ws, size_t ws_size,
                              hipStream_t stream) {
  const float* pf     = (const float*)d_in[0];  // [P,64] f32
  const int*   coords = (const int*)d_in[1];    // [P,4] int32 (b,z,y,x)
  const float* vnp    = (const float*)d_in[2];  // [P] f32
  const int B = kB;                              // fixed by problem config
  const int P = in_sizes[0] / kC;
  const int BS = B * kS;                         // 1,714,176
  float* out = (float*)d_out;

  const size_t map_bytes = (size_t)BS * sizeof(int);
  if (ws_size >= map_bytes) {
    int* map = (int*)d_ws;
    (void)hipMemsetAsync(map, 0xFF, map_bytes, stream);  // all -1
    scatter_idx_kernel<<<(P + 255) / 256, 256, 0, stream>>>(coords, map, P, BS);
    const int total4 = (B * kC * kS + B * kS) / 4;  // 27,855,360 float4s
    const int nthreads = total4 / 2;                // 13,927,680
    gather_fill_kernel<<<(nthreads + 255) / 256, 256, 0, stream>>>(
        map, pf, vnp, out, nthreads);
  } else {
    (void)hipMemsetAsync(out, 0, (size_t)out_size * sizeof(float), stream);
    direct_scatter_kernel<<<P, 64, 0, stream>>>(coords, pf, vnp, out, P, B);
  }
}

// Round 7
// 107.366 us; speedup vs baseline: 1.5352x; 1.5351x over previous
//
#include <hip/hip_runtime.h>

// PointPillarScatter: scatter sparse pillar features into a dense BEV grid.
// Grid: NX=432, NY=496, NZ=1, C=64, B=8, P=96000 pillars (5.6% occupancy).
// Out 0: [B, C, NY, NX] f32 ; Out 1: [B, 1, NY, NX] f32, concatenated flat.
//
// Round-7: EXACT round-2 shape (1 float4 per thread, 27.8M threads — the only
// 116.5us configuration; both 2-float4/thread variants were 164.8us), with a
// single variable changed: nontemporal output stores. The 446MB write stream
// is never re-read; streaming it past L2 leaves L2 to the map re-reads
// (446MB of L2 load traffic) and pf gathers.

namespace {

constexpr int kNX = 432;
constexpr int kNY = 496;
constexpr int kS  = kNX * kNY;   // 214272 spatial cells per sample
constexpr int kS4 = kS / 4;      // 53568 float4s per plane
constexpr int kC  = 64;
constexpr int kB  = 8;

typedef float f32x4 __attribute__((ext_vector_type(4)));

__global__ void scatter_idx_kernel(const int* __restrict__ coords,
                                   int* __restrict__ map,
                                   int P, int BS) {
  int p = blockIdx.x * blockDim.x + threadIdx.x;
  if (p >= P) return;
  // coords row p = (b, z, y, x) as int32
  int4 c = reinterpret_cast<const int4*>(coords)[p];
  long flat = (long)c.x * kS + (long)c.y + (long)c.z * kNX + (long)c.w;
  if (flat >= 0 && flat < (long)BS) map[(int)flat] = p;
}

// One thread = one output float4, swept linearly over the whole 446 MB.
// plane 0..511   -> out0 (b = plane>>6, c = plane&63)
// plane 512..519 -> out1 (b = plane-512)
__global__ __launch_bounds__(256) void gather_fill_kernel(
    const int* __restrict__ map,     // [B*S] pillar index or -1
    const float* __restrict__ pf,    // [P, 64]
    const float* __restrict__ vnp,   // [P]
    float* __restrict__ out,
    int total4) {
  int g = blockIdx.x * blockDim.x + threadIdx.x;
  if (g >= total4) return;
  int plane = g / kS4;               // const-div -> mul_hi
  int j = g - plane * kS4;           // float4 index within plane

  f32x4 v = (f32x4)(0.f);
  if (plane < kB * kC) {
    int b = plane >> 6;
    int c = plane & 63;
    int4 m = reinterpret_cast<const int4*>(map)[b * kS4 + j];
    if ((m.x >= 0) | (m.y >= 0) | (m.z >= 0) | (m.w >= 0)) {
      if (m.x >= 0) v.x = pf[m.x * kC + c];
      if (m.y >= 0) v.y = pf[m.y * kC + c];
      if (m.z >= 0) v.z = pf[m.z * kC + c];
      if (m.w >= 0) v.w = pf[m.w * kC + c];
    }
  } else {
    int b = plane - kB * kC;
    int4 m = reinterpret_cast<const int4*>(map)[b * kS4 + j];
    if (m.x >= 0) v.x = vnp[m.x];
    if (m.y >= 0) v.y = vnp[m.y];
    if (m.z >= 0) v.z = vnp[m.z];
    if (m.w >= 0) v.w = vnp[m.w];
  }
  // streaming store: evict-first / no L2 allocate; output is never re-read
  __builtin_nontemporal_store(v, reinterpret_cast<f32x4*>(out) + g);
}

// ---- fallback if ws_size is too small for the map: memset + direct scatter
__global__ void direct_scatter_kernel(const int* __restrict__ coords,
                                      const float* __restrict__ pf,
                                      const float* __restrict__ vnp,
                                      float* __restrict__ out,
                                      int P, int B) {
  int p = blockIdx.x;          // one wave per pillar
  int c = threadIdx.x;         // 64 channels
  if (p >= P) return;
  int4 cc = reinterpret_cast<const int4*>(coords)[p];
  int b = cc.x;
  int s = cc.y + cc.z * kNX + cc.w;
  out[(b * kC + c) * kS + s] = pf[p * kC + c];
  if (c == 0) out[B * kC * kS + b * kS + s] = vnp[p];
}

}  // namespace

extern "C" void kernel_launch(void* const* d_in, const int* in_sizes, int n_in,
                              void* d_out, int out_size, void* d_ws, size_t ws_size,
                              hipStream_t stream) {
  const float* pf     = (const float*)d_in[0];  // [P,64] f32
  const int*   coords = (const int*)d_in[1];    // [P,4] int32 (b,z,y,x)
  const float* vnp    = (const float*)d_in[2];  // [P] f32
  const int B = kB;                              // fixed by problem config
  const int P = in_sizes[0] / kC;
  const int BS = B * kS;                         // 1,714,176
  float* out = (float*)d_out;

  const size_t map_bytes = (size_t)BS * sizeof(int);
  if (ws_size >= map_bytes) {
    int* map = (int*)d_ws;
    (void)hipMemsetAsync(map, 0xFF, map_bytes, stream);  // all -1
    scatter_idx_kernel<<<(P + 255) / 256, 256, 0, stream>>>(coords, map, P, BS);
    const int total4 = (B * kC * kS + B * kS) / 4;  // 27,855,360 float4s
    gather_fill_kernel<<<(total4 + 255) / 256, 256, 0, stream>>>(
        map, pf, vnp, out, total4);
  } else {
    (void)hipMemsetAsync(out, 0, (size_t)out_size * sizeof(float), stream);
    direct_scatter_kernel<<<P, 64, 0, stream>>>(coords, pf, vnp, out, P, B);
  }
}